// Round 10
// baseline (213.326 us; speedup 1.0000x reference)
//
#include <hip/hip_runtime.h>
#include <hip/hip_bf16.h>

#define BB   32
#define NN   2048
#define DIN  128
#define DOUT 256
#define DCTX 259

// ---- workspace layout (float-slot offsets) ----
#define OFF_AB   0u          // A  bf16 [B][256][256] (dead before kF)
#define OFF_WMB  16777216u   // WM bf16 [B][256 e][128 i] = 524288
#define OFF_WLB  17301504u   // W_layer bf16 [256 o][128 i] = 16384
#define OFF_WLTB 17317888u   // W_layer^T bf16 [128 i][256 o] = 16384
#define OFF_WTCB 17334272u   // W_tc bf16 [256 e][256 o] = 32768
#define OFF_G    17367040u
#define OFF_HB   17375232u
#define OFF_TB   17383424u
#define OFF_P1   17655296u   // BN partial s1 [32 b][2048 n] fp32
#define OFF_P2   17720832u   // BN partial s2 [32 b][2048 n] fp32
#define OFF_KS   17786368u   // ks fp32 [32 b][256]
#define OFF_VS   17794560u   // vs fp32 [32 b][256]
// end 17802752 slots ≈ 71.2 MB

typedef short bf16x8 __attribute__((ext_vector_type(8)));
typedef float f32x4  __attribute__((ext_vector_type(4)));

static __device__ inline unsigned short f2bf(float f) {
    __hip_bfloat16 h = __float2bfloat16(f);
    return *(unsigned short*)&h;
}
static __device__ inline float bf2f(unsigned short u) {
    unsigned v = ((unsigned)u) << 16;
    float f;
    __builtin_memcpy(&f, &v, 4);
    return f;
}

// Merged pack + ctx-GEMV. Blocks 0..9: bf16 weight packing. Blocks 10..73:
// GEMV tiles (LDS-staged, coalesced).
__global__ __launch_bounds__(256) void kW(const float* __restrict__ Wl,
                                          const float* __restrict__ Wtc,
                                          const float* __restrict__ Wk,
                                          const float* __restrict__ Wv,
                                          const float* __restrict__ Wg,
                                          const float* __restrict__ Whb,
                                          const float* __restrict__ ctx,
                                          const float* __restrict__ bg,
                                          float* __restrict__ ws) {
    const unsigned bb = blockIdx.x, t = threadIdx.x;
    __shared__ float ctxs[32][260];
    __shared__ float wt[16][260];

    if (bb < 8u) {
        unsigned base = bb * 8192u;
        unsigned short* dst = (unsigned short*)(ws + OFF_WTCB);
#pragma unroll
        for (int j = 0; j < 32; j++) {
            unsigned i = base + (unsigned)j * 256u + t;
            dst[i] = f2bf(Wtc[i]);
        }
        return;
    } else if (bb == 8u) {
        unsigned short* dst = (unsigned short*)(ws + OFF_WLTB);   // [i][o]
        for (unsigned idx = t; idx < 32768u; idx += 256u) {
            unsigned i = idx >> 8, o = idx & 255u;
            dst[idx] = f2bf(Wl[o * 128u + i]);
        }
        return;
    } else if (bb == 9u) {
        unsigned short* dst = (unsigned short*)(ws + OFF_WLB);    // [o][i]
        for (unsigned idx = t; idx < 32768u; idx += 256u) dst[idx] = f2bf(Wl[idx]);
        return;
    }

    // ---- GEMV tile block ----
    const int j = bb - 10;            // 0..63
    const int m = j >> 4;             // matrix select
    const int o0 = (j & 15) * 16;
    const float* Wm; int C;
    if (m == 0)      { Wm = Wk;  C = 256; }
    else if (m == 1) { Wm = Wv;  C = 256; }
    else if (m == 2) { Wm = Wg;  C = DCTX; }
    else             { Wm = Whb; C = DCTX; }

    for (int i = t; i < 32 * 260; i += 256) {
        int b2 = i / 260, c = i - b2 * 260;
        ctxs[b2][c] = (c < DCTX) ? ctx[b2 * DCTX + c] : 0.f;
    }
    for (int i = t; i < 16 * C; i += 256) {
        int r = i / C, c = i - r * C;
        wt[r][c] = Wm[(size_t)(o0 + r) * C + c];
    }
    __syncthreads();

    const int ol = t & 15, b2 = t >> 4;       // each thread: 2 batches
    float s0 = 0.f, s1 = 0.f;
#pragma unroll 8
    for (int c = 0; c < C; c++) {
        float w = wt[ol][c];
        s0 += w * ctxs[b2][c];
        s1 += w * ctxs[b2 + 16][c];
    }
    const int o = o0 + ol;
    if (m == 0) {
        ws[OFF_KS + b2 * DOUT + o] = s0;
        ws[OFF_KS + (b2 + 16) * DOUT + o] = s1;
    } else if (m == 1) {
        ws[OFF_VS + b2 * DOUT + o] = s0;
        ws[OFF_VS + (b2 + 16) * DOUT + o] = s1;
    } else if (m == 2) {
        float bgo = bg[o];
        ws[OFF_G + b2 * DOUT + o] = 1.f / (1.f + __expf(-(s0 + bgo)));
        ws[OFF_G + (b2 + 16) * DOUT + o] = 1.f / (1.f + __expf(-(s1 + bgo)));
    } else {
        ws[OFF_HB + b2 * DOUT + o] = s0;
        ws[OFF_HB + (b2 + 16) * DOUT + o] = s1;
    }
}

// Softmax + A only. 1024 threads, grid B.
__global__ __launch_bounds__(1024) void kP(float* __restrict__ ws) {
    const int b = blockIdx.x, t = threadIdx.x;
    const int o = t & 255, q = t >> 8;
    __shared__ __align__(16) float ks[256], vs[256], rms[256], ris[256];
    __shared__ float pm[1024], ps[1024];
    if (t < 256)            ks[t] = ws[OFF_KS + b * DOUT + t];
    else if (t < 512)       vs[t - 256] = ws[OFF_VS + b * DOUT + (t - 256)];
    __syncthreads();

    const float ko = ks[o];
    const float4* vs4 = (const float4*)vs;
    float pmax = -1e30f;
#pragma unroll 4
    for (int j = q * 16; j < q * 16 + 16; j++) {
        float4 v = vs4[j];
        pmax = fmaxf(pmax, fmaxf(fmaxf(ko * v.x, ko * v.y), fmaxf(ko * v.z, ko * v.w)));
    }
    pm[q * 256 + o] = pmax;
    __syncthreads();
    float m = fmaxf(fmaxf(pm[o], pm[256 + o]), fmaxf(pm[512 + o], pm[768 + o]));
    float psum = 0.f;
#pragma unroll 4
    for (int j = q * 16; j < q * 16 + 16; j++) {
        float4 v = vs4[j];
        psum += __expf(ko * v.x - m) + __expf(ko * v.y - m)
              + __expf(ko * v.z - m) + __expf(ko * v.w - m);
    }
    ps[q * 256 + o] = psum;
    __syncthreads();
    float ri = 1.f / (ps[o] + ps[256 + o] + ps[512 + o] + ps[768 + o]);
    if (q == 0) { rms[o] = m; ris[o] = ri; }
    __syncthreads();

    const float ve = vs[o];
    float cp = 0.f;
#pragma unroll 4
    for (int o2 = q * 64; o2 < q * 64 + 64; o2++)
        cp += __expf(ks[o2] * ve - rms[o2]) * ris[o2];
    pm[q * 256 + o] = cp;
    __syncthreads();
    float ci = 1.f / (1e-9f + pm[o] + pm[256 + o] + pm[512 + o] + pm[768 + o]);
    unsigned short* Ab = (unsigned short*)(ws + OFF_AB) + (size_t)b * 65536u;
#pragma unroll 4
    for (int o2 = q * 64; o2 < q * 64 + 64; o2++) {
        float a = __expf(ks[o2] * ve - rms[o2]) * ris[o2] * ci;
        Ab[o2 * 256 + o] = f2bf(a);
    }
}

// Fused k4m+k5m, 64-row et-quarters. Mt in LDS (XOR-swizzled), then
// WM = Mt @ Wl^T and tb GEMV. grid (4 e-quarters, B), 512 threads.
__global__ __launch_bounds__(512) void k45(const float* __restrict__ bl,
                                           const float* __restrict__ btc,
                                           float* __restrict__ ws) {
    const int t = threadIdx.x, wid = t >> 6, l = t & 63;
    const int b = blockIdx.y, et = blockIdx.x;
    const int lrow = l & 15, lk = l >> 4;
    __shared__ unsigned short Mt[64 * 256];   // 32 KB, swizzled: col ^ ((row&7)<<3)
    const unsigned short* Wtcb = (const unsigned short*)(ws + OFF_WTCB);

    // ---- phase A: Mt rows [et*64, et*64+64), waves 2 rows x 4 cols ----
    {
        const unsigned short* Ab = (const unsigned short*)(ws + OFF_AB) + (size_t)b * 65536u;
        const int w_r = wid >> 2, w_c = wid & 3;
        const int rbase = et * 64 + w_r * 32;
        const int colbase = w_c * 64;
        f32x4 acc[2][4];
#pragma unroll
        for (int i = 0; i < 2; i++)
#pragma unroll
            for (int c = 0; c < 4; c++) acc[i][c] = (f32x4){0.f, 0.f, 0.f, 0.f};
        const unsigned short* ar0 = Wtcb + (rbase + lrow) * 256;
#pragma unroll
        for (int kk = 0; kk < 8; kk++) {
            int ko = kk * 32 + lk * 8;
            bf16x8 a0 = *(const bf16x8*)(ar0 + ko);
            bf16x8 a1 = *(const bf16x8*)(ar0 + 16 * 256 + ko);
            bf16x8 bfr[4];
#pragma unroll
            for (int c = 0; c < 4; c++)
                bfr[c] = *(const bf16x8*)(Ab + (colbase + c * 16 + lrow) * 256 + ko);
#pragma unroll
            for (int c = 0; c < 4; c++) {
                acc[0][c] = __builtin_amdgcn_mfma_f32_16x16x32_bf16(a0, bfr[c], acc[0][c], 0, 0, 0);
                acc[1][c] = __builtin_amdgcn_mfma_f32_16x16x32_bf16(a1, bfr[c], acc[1][c], 0, 0, 0);
            }
        }
#pragma unroll
        for (int t2 = 0; t2 < 2; t2++)
#pragma unroll
            for (int c = 0; c < 4; c++)
#pragma unroll
                for (int r = 0; r < 4; r++) {
                    int grow = rbase + t2 * 16 + lk * 4 + r;
                    int col = colbase + c * 16 + lrow;
                    float idv = bf2f(Wtcb[grow * 256 + col]);
                    int rl = grow - et * 64;
                    Mt[rl * 256 + (col ^ ((rl & 7) << 3))] = f2bf(idv - acc[t2][c][r]);
                }
    }
    __syncthreads();
    // ---- phase B: WM rows [et*64..+64) = Mt @ Wl^T ----
    {
        const unsigned short* Wltb = (const unsigned short*)(ws + OFF_WLTB);
        const int w_r = wid >> 2, w_c = wid & 3;
        const int rl0 = w_r * 32;
        const int colb = w_c * 32;
        f32x4 acc[2][2];
#pragma unroll
        for (int i = 0; i < 2; i++)
#pragma unroll
            for (int c = 0; c < 2; c++) acc[i][c] = (f32x4){0.f, 0.f, 0.f, 0.f};
        const int arow0 = rl0 + lrow, arow1 = rl0 + 16 + lrow;
        const int asw0 = (arow0 & 7) << 3, asw1 = (arow1 & 7) << 3;
#pragma unroll
        for (int kk = 0; kk < 8; kk++) {
            int ko = kk * 32 + lk * 8;
            bf16x8 a0 = *(const bf16x8*)(Mt + arow0 * 256 + (ko ^ asw0));
            bf16x8 a1 = *(const bf16x8*)(Mt + arow1 * 256 + (ko ^ asw1));
            bf16x8 bfr[2];
#pragma unroll
            for (int c = 0; c < 2; c++)
                bfr[c] = *(const bf16x8*)(Wltb + (colb + c * 16 + lrow) * 256 + ko);
#pragma unroll
            for (int c = 0; c < 2; c++) {
                acc[0][c] = __builtin_amdgcn_mfma_f32_16x16x32_bf16(a0, bfr[c], acc[0][c], 0, 0, 0);
                acc[1][c] = __builtin_amdgcn_mfma_f32_16x16x32_bf16(a1, bfr[c], acc[1][c], 0, 0, 0);
            }
        }
        unsigned short* WMBp = (unsigned short*)(ws + OFF_WMB) + (size_t)b * 32768u;
#pragma unroll
        for (int t2 = 0; t2 < 2; t2++)
#pragma unroll
            for (int c = 0; c < 2; c++)
#pragma unroll
                for (int r = 0; r < 4; r++) {
                    int row = et * 64 + rl0 + t2 * 16 + lk * 4 + r;
                    int col = colb + c * 16 + lrow;
                    WMBp[row * 128 + col] = f2bf(acc[t2][c][r]);
                }
    }
    // ---- tb bias GEMV from LDS Mt ----
    if (t < 64) {
        const int rl = t;
        const int sw = (rl & 7) << 3;
        float s = 0.f;
#pragma unroll 4
        for (int j = 0; j < 32; j++) {
            bf16x8 ch = *(const bf16x8*)(Mt + rl * 256 + ((j * 8) ^ sw));
#pragma unroll
            for (int u = 0; u < 8; u++) s += bl[j * 8 + u] * bf2f((unsigned short)ch[u]);
        }
        ws[OFF_TB + b * DOUT + et * 64 + rl] = s + btc[et * 64 + rl];
    }
}

#define LDP 136

// BN-stats GEMM: recompute tt = x @ WM^T + tb, reduce rows to (s1,s2), write
// atomic-free partials part[b][n]. grid (32 b, 32 nt), 256 thr. (R8-proven.)
__global__ __launch_bounds__(256) void kS(const float* __restrict__ x,
                                          float* __restrict__ ws) {
    const int t = threadIdx.x;
    const int wid = t >> 6, l = t & 63;
    const int b = blockIdx.x, nt = blockIdx.y;
    const int n0 = nt * 64;
    const int lrow = l & 15, lk = l >> 4;
    __shared__ unsigned short xs[64 * LDP];
    __shared__ float sp1[4][64], sp2[4][64];

    const float4* xg = (const float4*)(x + (size_t)(b * NN + n0) * DIN);
#pragma unroll
    for (int it = 0; it < 8; it++) {
        int idx = it * 256 + t;
        int row = idx >> 5, kq = idx & 31;
        float4 v = xg[idx];
        ushort4 u;
        u.x = f2bf(v.x); u.y = f2bf(v.y); u.z = f2bf(v.z); u.w = f2bf(v.w);
        *(ushort4*)(xs + row * LDP + kq * 4) = u;
    }
    __syncthreads();

    const int colbase = wid * 64;
    f32x4 acc[4][4];
#pragma unroll
    for (int rt = 0; rt < 4; rt++)
#pragma unroll
        for (int ct = 0; ct < 4; ct++) acc[rt][ct] = (f32x4){0.f, 0.f, 0.f, 0.f};
    {
        const unsigned short* wb = (const unsigned short*)(ws + OFF_WMB) + (size_t)b * 32768u;
#pragma unroll
        for (int kk = 0; kk < 4; kk++) {
            int ko = kk * 32 + lk * 8;
            bf16x8 a[4];
#pragma unroll
            for (int rt = 0; rt < 4; rt++)
                a[rt] = *(const bf16x8*)(xs + (rt * 16 + lrow) * LDP + ko);
            bf16x8 bf[4];
#pragma unroll
            for (int ct = 0; ct < 4; ct++)
                bf[ct] = *(const bf16x8*)(wb + (size_t)(colbase + ct * 16 + lrow) * DIN + ko);
#pragma unroll
            for (int rt = 0; rt < 4; rt++)
#pragma unroll
                for (int ct = 0; ct < 4; ct++)
                    acc[rt][ct] = __builtin_amdgcn_mfma_f32_16x16x32_bf16(a[rt], bf[ct], acc[rt][ct], 0, 0, 0);
        }
#pragma unroll
        for (int ct = 0; ct < 4; ct++) {
            float bv = ws[OFF_TB + b * DOUT + colbase + ct * 16 + lrow];
#pragma unroll
            for (int rt = 0; rt < 4; rt++)
#pragma unroll
                for (int r = 0; r < 4; r++) acc[rt][ct][r] += bv;
        }
    }

    float s1[4][4], s2[4][4];
#pragma unroll
    for (int rt = 0; rt < 4; rt++)
#pragma unroll
        for (int r = 0; r < 4; r++) { s1[rt][r] = 0.f; s2[rt][r] = 0.f; }
#pragma unroll
    for (int rt = 0; rt < 4; rt++)
#pragma unroll
        for (int ct = 0; ct < 4; ct++)
#pragma unroll
            for (int r = 0; r < 4; r++) {
                float v = acc[rt][ct][r];
                s1[rt][r] += v; s2[rt][r] += v * v;
            }
#pragma unroll
    for (int off = 1; off < 16; off <<= 1) {
#pragma unroll
        for (int rt = 0; rt < 4; rt++)
#pragma unroll
            for (int r = 0; r < 4; r++) {
                s1[rt][r] += __shfl_xor(s1[rt][r], off, 64);
                s2[rt][r] += __shfl_xor(s2[rt][r], off, 64);
            }
    }
    if (lrow == 0) {
#pragma unroll
        for (int rt = 0; rt < 4; rt++)
#pragma unroll
            for (int r = 0; r < 4; r++) {
                int nidx = rt * 16 + lk * 4 + r;
                sp1[wid][nidx] = s1[rt][r];
                sp2[wid][nidx] = s2[rt][r];
            }
    }
    __syncthreads();
    if (t < 64) {
        float S1 = sp1[0][t] + sp1[1][t] + sp1[2][t] + sp1[3][t];
        float S2 = sp2[0][t] + sp2[1][t] + sp2[2][t] + sp2[3][t];
        ws[OFF_P1 + (size_t)b * NN + n0 + t] = S1;
        ws[OFF_P2 + (size_t)b * NN + n0 + t] = S2;
    }
}

// Dual-GEMM + BN finalize + epilogue, MERGED kk-loop: shared a-frags feed both
// weight streams (bM+bL loads in flight together -> 2x memory ILP per iter).
// 32-row tiles keep VGPR ~120 (acc 32 + acc0 32 + a 8 + bM 16 + bL 16) ->
// 4 waves/SIMD uncapped. grid (32 b, 64 nt), no cross-block sync.
__global__ __launch_bounds__(256) void kF(const float* __restrict__ x,
                                          const float* __restrict__ bl,
                                          const float* __restrict__ gamma,
                                          const float* __restrict__ beta,
                                          float* __restrict__ out,
                                          float* __restrict__ ws) {
    const int t = threadIdx.x;
    const int wid = t >> 6, l = t & 63;
    const int b = blockIdx.x;
    const int nt = blockIdx.y;
    const int n0 = nt * 32;
    const int lrow = l & 15, lk = l >> 4;
    __shared__ unsigned short xs[32 * LDP];
    __shared__ float sq1[8][32], sq2[8][32];
    __shared__ float scs[32], shs[32];

    // issue x loads first; BN partial fold overlaps their latency
    const float4* xg = (const float4*)(x + (size_t)(b * NN + n0) * DIN);
    float4 xv[4];
#pragma unroll
    for (int it = 0; it < 4; it++) xv[it] = xg[it * 256 + t];

    {
        int n = t & 31, g = t >> 5;          // 8 groups x 4 batches
        float S1 = 0.f, S2 = 0.f;
#pragma unroll
        for (int b2 = g * 4; b2 < g * 4 + 4; b2++) {
            S1 += ws[OFF_P1 + (size_t)b2 * NN + n0 + n];
            S2 += ws[OFF_P2 + (size_t)b2 * NN + n0 + n];
        }
        sq1[g][n] = S1; sq2[g][n] = S2;
    }
    __syncthreads();
    if (t < 32) {
        float S1 = 0.f, S2 = 0.f;
#pragma unroll
        for (int g = 0; g < 8; g++) { S1 += sq1[g][t]; S2 += sq2[g][t]; }
        float mean = S1 * (1.f / 8192.f);
        float var  = S2 * (1.f / 8192.f) - mean * mean;
        float sc = gamma[n0 + t] * rsqrtf(fmaxf(var, 0.f) + 1e-5f);
        scs[t] = sc;
        shs[t] = beta[n0 + t] - mean * sc;
    }
#pragma unroll
    for (int it = 0; it < 4; it++) {
        int idx = it * 256 + t;
        int row = idx >> 5, kq = idx & 31;
        ushort4 u;
        u.x = f2bf(xv[it].x); u.y = f2bf(xv[it].y); u.z = f2bf(xv[it].z); u.w = f2bf(xv[it].w);
        *(ushort4*)(xs + row * LDP + kq * 4) = u;
    }
    __syncthreads();

    const int colbase = wid * 64;

    // ---- merged dual GEMM: per kk, a0/a1 shared; bM+bL streams in flight ----
    f32x4 acc[2][4], acc0[2][4];
#pragma unroll
    for (int rt = 0; rt < 2; rt++)
#pragma unroll
        for (int ct = 0; ct < 4; ct++) {
            acc[rt][ct]  = (f32x4){0.f, 0.f, 0.f, 0.f};
            acc0[rt][ct] = (f32x4){0.f, 0.f, 0.f, 0.f};
        }
    {
        const unsigned short* wbM = (const unsigned short*)(ws + OFF_WMB) + (size_t)b * 32768u;
        const unsigned short* wbL = (const unsigned short*)(ws + OFF_WLB);
#pragma unroll
        for (int kk = 0; kk < 4; kk++) {
            int ko = kk * 32 + lk * 8;
            bf16x8 a0 = *(const bf16x8*)(xs + lrow * LDP + ko);
            bf16x8 a1 = *(const bf16x8*)(xs + (16 + lrow) * LDP + ko);
            bf16x8 bM[4], bL[4];
#pragma unroll
            for (int ct = 0; ct < 4; ct++)
                bM[ct] = *(const bf16x8*)(wbM + (size_t)(colbase + ct * 16 + lrow) * DIN + ko);
#pragma unroll
            for (int ct = 0; ct < 4; ct++)
                bL[ct] = *(const bf16x8*)(wbL + (size_t)(colbase + ct * 16 + lrow) * DIN + ko);
#pragma unroll
            for (int ct = 0; ct < 4; ct++) {
                acc[0][ct]  = __builtin_amdgcn_mfma_f32_16x16x32_bf16(a0, bM[ct], acc[0][ct], 0, 0, 0);
                acc[1][ct]  = __builtin_amdgcn_mfma_f32_16x16x32_bf16(a1, bM[ct], acc[1][ct], 0, 0, 0);
                acc0[0][ct] = __builtin_amdgcn_mfma_f32_16x16x32_bf16(a0, bL[ct], acc0[0][ct], 0, 0, 0);
                acc0[1][ct] = __builtin_amdgcn_mfma_f32_16x16x32_bf16(a1, bL[ct], acc0[1][ct], 0, 0, 0);
            }
        }
#pragma unroll
        for (int ct = 0; ct < 4; ct++) {
            float bvM = ws[OFF_TB + b * DOUT + colbase + ct * 16 + lrow];
            float bvL = bl[colbase + ct * 16 + lrow];
#pragma unroll
            for (int rt = 0; rt < 2; rt++)
#pragma unroll
                for (int r = 0; r < 4; r++) {
                    acc[rt][ct][r]  += bvM;
                    acc0[rt][ct][r] += bvL;
                }
        }
    }

    // ---- epilogue straight from registers: out = (x1 + relu(bn(tt)))*g + hb ----
    float gv[4], hbv[4];
#pragma unroll
    for (int ct = 0; ct < 4; ct++) {
        int o = colbase + ct * 16 + lrow;
        gv[ct]  = ws[OFF_G  + b * DOUT + o];
        hbv[ct] = ws[OFF_HB + b * DOUT + o];
    }
#pragma unroll
    for (int rt = 0; rt < 2; rt++)
#pragma unroll
        for (int r = 0; r < 4; r++) {
            int nidx = rt * 16 + lk * 4 + r;
            float sc = scs[nidx], sh = shs[nidx];
            int n = n0 + nidx;
#pragma unroll
            for (int ct = 0; ct < 4; ct++) {
                int o = colbase + ct * 16 + lrow;
                float rv = fmaxf(acc[rt][ct][r] * sc + sh, 0.f);
                out[(size_t)((b * NN + n) * DOUT) + o] = (acc0[rt][ct][r] + rv) * gv[ct] + hbv[ct];
            }
        }
}

extern "C" void kernel_launch(void* const* d_in, const int* in_sizes, int n_in,
                              void* d_out, int out_size, void* d_ws, size_t ws_size,
                              hipStream_t stream) {
    const float* ctx   = (const float*)d_in[0];
    const float* x     = (const float*)d_in[1];
    const float* Wl    = (const float*)d_in[2];
    const float* bl    = (const float*)d_in[3];
    const float* Whb   = (const float*)d_in[4];
    const float* Wg    = (const float*)d_in[5];
    const float* bg    = (const float*)d_in[6];
    const float* Wk    = (const float*)d_in[7];
    const float* Wv    = (const float*)d_in[8];
    const float* Wtc   = (const float*)d_in[9];
    const float* btc   = (const float*)d_in[10];
    const float* gamma = (const float*)d_in[11];
    const float* beta  = (const float*)d_in[12];
    float* out = (float*)d_out;
    float* ws  = (float*)d_ws;

    kW  <<<74, 256, 0, stream>>>(Wl, Wtc, Wk, Wv, Wg, Whb, ctx, bg, ws);
    kP  <<<BB, 1024, 0, stream>>>(ws);
    k45 <<<dim3(4, BB), 512, 0, stream>>>(bl, btc, ws);
    kS  <<<dim3(BB, 32), 256, 0, stream>>>(x, ws);
    kF  <<<dim3(BB, 64), 256, 0, stream>>>(x, bl, gamma, beta, out, ws);
}

// Round 11
// 200.259 us; speedup vs baseline: 1.0652x; 1.0652x over previous
//
#include <hip/hip_runtime.h>
#include <hip/hip_bf16.h>

#define BB   32
#define NN   2048
#define DIN  128
#define DOUT 256
#define DCTX 259

// ---- workspace layout (float-slot offsets) ----
#define OFF_WMB  16777216u   // WM bf16 [B][256 e][128 i] = 524288
#define OFF_WLB  17301504u   // W_layer bf16 [256 o][128 i] = 16384
#define OFF_WLTB 17317888u   // W_layer^T bf16 [128 i][256 o] = 16384
#define OFF_WTCB 17334272u   // W_tc bf16 [256 e][256 o] = 32768
#define OFF_G    17367040u
#define OFF_HB   17375232u
#define OFF_TB   17383424u
#define OFF_P1   17655296u   // BN partial s1 [32 b][2048 n] fp32
#define OFF_P2   17720832u   // BN partial s2 [32 b][2048 n] fp32
#define OFF_KS   17786368u   // ks fp32 [32 b][256]
#define OFF_VS   17794560u   // vs fp32 [32 b][256]
#define OFF_CNT  17802752u   // [32 nt] arrival counters, padded 32 uints (128B) apart
// end 17803776 slots ≈ 71.2 MB

typedef short bf16x8 __attribute__((ext_vector_type(8)));
typedef float f32x4  __attribute__((ext_vector_type(4)));

static __device__ inline unsigned short f2bf(float f) {
    __hip_bfloat16 h = __float2bfloat16(f);
    return *(unsigned short*)&h;
}
static __device__ inline float bf2f(unsigned short u) {
    unsigned v = ((unsigned)u) << 16;
    float f;
    __builtin_memcpy(&f, &v, 4);
    return f;
}

// Merged pack + ctx-GEMV + counter zeroing. Blocks 0..9: bf16 weight packing.
// Blocks 10..73: GEMV tiles (LDS-staged, coalesced). Block 74: zero counters.
__global__ __launch_bounds__(256) void kW(const float* __restrict__ Wl,
                                          const float* __restrict__ Wtc,
                                          const float* __restrict__ Wk,
                                          const float* __restrict__ Wv,
                                          const float* __restrict__ Wg,
                                          const float* __restrict__ Whb,
                                          const float* __restrict__ ctx,
                                          const float* __restrict__ bg,
                                          float* __restrict__ ws) {
    const unsigned bb = blockIdx.x, t = threadIdx.x;
    __shared__ float ctxs[32][260];
    __shared__ float wt[16][260];

    if (bb < 8u) {
        unsigned base = bb * 8192u;
        unsigned short* dst = (unsigned short*)(ws + OFF_WTCB);
#pragma unroll
        for (int j = 0; j < 32; j++) {
            unsigned i = base + (unsigned)j * 256u + t;
            dst[i] = f2bf(Wtc[i]);
        }
        return;
    } else if (bb == 8u) {
        unsigned short* dst = (unsigned short*)(ws + OFF_WLTB);   // [i][o]
        for (unsigned idx = t; idx < 32768u; idx += 256u) {
            unsigned i = idx >> 8, o = idx & 255u;
            dst[idx] = f2bf(Wl[o * 128u + i]);
        }
        return;
    } else if (bb == 9u) {
        unsigned short* dst = (unsigned short*)(ws + OFF_WLB);    // [o][i]
        for (unsigned idx = t; idx < 32768u; idx += 256u) dst[idx] = f2bf(Wl[idx]);
        return;
    } else if (bb == 74u) {
        unsigned* c = (unsigned*)(ws + OFF_CNT);
        for (unsigned i = t; i < 1024u; i += 256u) c[i] = 0u;
        return;
    }

    // ---- GEMV tile block ----
    const int j = bb - 10;            // 0..63
    const int m = j >> 4;             // matrix select
    const int o0 = (j & 15) * 16;
    const float* Wm; int C;
    if (m == 0)      { Wm = Wk;  C = 256; }
    else if (m == 1) { Wm = Wv;  C = 256; }
    else if (m == 2) { Wm = Wg;  C = DCTX; }
    else             { Wm = Whb; C = DCTX; }

    for (int i = t; i < 32 * 260; i += 256) {
        int b2 = i / 260, c = i - b2 * 260;
        ctxs[b2][c] = (c < DCTX) ? ctx[b2 * DCTX + c] : 0.f;
    }
    for (int i = t; i < 16 * C; i += 256) {
        int r = i / C, c = i - r * C;
        wt[r][c] = Wm[(size_t)(o0 + r) * C + c];
    }
    __syncthreads();

    const int ol = t & 15, b2 = t >> 4;       // each thread: 2 batches
    float s0 = 0.f, s1 = 0.f;
#pragma unroll 8
    for (int c = 0; c < C; c++) {
        float w = wt[ol][c];
        s0 += w * ctxs[b2][c];
        s1 += w * ctxs[b2 + 16][c];
    }
    const int o = o0 + ol;
    if (m == 0) {
        ws[OFF_KS + b2 * DOUT + o] = s0;
        ws[OFF_KS + (b2 + 16) * DOUT + o] = s1;
    } else if (m == 1) {
        ws[OFF_VS + b2 * DOUT + o] = s0;
        ws[OFF_VS + (b2 + 16) * DOUT + o] = s1;
    } else if (m == 2) {
        float bgo = bg[o];
        ws[OFF_G + b2 * DOUT + o] = 1.f / (1.f + __expf(-(s0 + bgo)));
        ws[OFF_G + (b2 + 16) * DOUT + o] = 1.f / (1.f + __expf(-(s1 + bgo)));
    } else {
        ws[OFF_HB + b2 * DOUT + o] = s0;
        ws[OFF_HB + (b2 + 16) * DOUT + o] = s1;
    }
}

// Merged kP+k45 (A never materialized): per block, softmax stats (512-thread
// port of proven kP), then phase A with Ab CHUNKS generated on-the-fly in LDS
// (16 exps/thread/chunk, padded rows: 2-way bank only), Mt in LDS (XOR-swz),
// phase B WM = Mt @ Wl^T + tb GEMV (R10-k45 verbatim). grid (4 et, 32 b), 512 thr.
__global__ __launch_bounds__(512) void kQ(const float* __restrict__ bl,
                                          const float* __restrict__ btc,
                                          float* __restrict__ ws) {
    const int t = threadIdx.x, wid = t >> 6, l = t & 63;
    const int b = blockIdx.y, et = blockIdx.x;
    const int lrow = l & 15, lk = l >> 4;
    __shared__ unsigned short Mt[64 * 256];     // 32 KB, swz: col ^ ((row&7)<<3)
    __shared__ unsigned short Abc[256 * 40];    // 20 KB chunk, rows padded to 40
    __shared__ __align__(16) float ks[256], vs[256], rms[256], ris[256], ci[256];
    __shared__ float pm[512], ps[512];
    const unsigned short* Wtcb = (const unsigned short*)(ws + OFF_WTCB);

    // ---- softmax stats (kP structure, q 2-way) ----
    if (t < 256)      ks[t] = ws[OFF_KS + b * DOUT + t];
    else              vs[t - 256] = ws[OFF_VS + b * DOUT + (t - 256)];
    __syncthreads();
    const int o = t & 255, q = t >> 8;
    {
        const float ko_ = ks[o];
        const float4* vs4 = (const float4*)vs;
        float pmax = -1e30f;
#pragma unroll 4
        for (int j = q * 32; j < q * 32 + 32; j++) {
            float4 v = vs4[j];
            pmax = fmaxf(pmax, fmaxf(fmaxf(ko_ * v.x, ko_ * v.y), fmaxf(ko_ * v.z, ko_ * v.w)));
        }
        pm[t] = pmax;
        __syncthreads();
        float m = fmaxf(pm[o], pm[256 + o]);
        float psum = 0.f;
#pragma unroll 4
        for (int j = q * 32; j < q * 32 + 32; j++) {
            float4 v = vs4[j];
            psum += __expf(ko_ * v.x - m) + __expf(ko_ * v.y - m)
                  + __expf(ko_ * v.z - m) + __expf(ko_ * v.w - m);
        }
        ps[t] = psum;
        __syncthreads();
        if (q == 0) { rms[o] = m; ris[o] = 1.f / (ps[o] + ps[256 + o]); }
        __syncthreads();
        const float ve = vs[o];
        float cp = 0.f;
#pragma unroll 4
        for (int o2 = q * 128; o2 < q * 128 + 128; o2++)
            cp += __expf(ks[o2] * ve - rms[o2]) * ris[o2];
        pm[t] = cp;
        __syncthreads();
        if (q == 0) ci[o] = 1.f / (1e-9f + pm[o] + pm[256 + o]);
        __syncthreads();
    }

    // ---- phase A: Mt rows [et*64..+64) with on-the-fly Ab chunks ----
    const int w_r = wid >> 2, w_c = wid & 3;
    {
        const int rbase = et * 64 + w_r * 32;
        const int colbase = w_c * 64;
        f32x4 acc[2][4];
#pragma unroll
        for (int i = 0; i < 2; i++)
#pragma unroll
            for (int c = 0; c < 4; c++) acc[i][c] = (f32x4){0.f, 0.f, 0.f, 0.f};
        const unsigned short* ar0 = Wtcb + (rbase + lrow) * 256;
        const int o2 = t & 255, h = t >> 8;
        const float k2 = ks[o2], rm = rms[o2], ri = ris[o2];
        for (int kk = 0; kk < 8; kk++) {
            // build chunk: Abc[o2][c] = A[o2][e = kk*32 + c]
#pragma unroll 8
            for (int j = 0; j < 16; j++) {
                int e = kk * 32 + h * 16 + j;
                Abc[o2 * 40 + h * 16 + j] = f2bf(__expf(k2 * vs[e] - rm) * ri * ci[e]);
            }
            __syncthreads();
            int ko = kk * 32 + lk * 8;
            bf16x8 a0 = *(const bf16x8*)(ar0 + ko);
            bf16x8 a1 = *(const bf16x8*)(ar0 + 16 * 256 + ko);
            bf16x8 bfr[4];
#pragma unroll
            for (int c = 0; c < 4; c++)
                bfr[c] = *(const bf16x8*)(Abc + (colbase + c * 16 + lrow) * 40 + lk * 8);
#pragma unroll
            for (int c = 0; c < 4; c++) {
                acc[0][c] = __builtin_amdgcn_mfma_f32_16x16x32_bf16(a0, bfr[c], acc[0][c], 0, 0, 0);
                acc[1][c] = __builtin_amdgcn_mfma_f32_16x16x32_bf16(a1, bfr[c], acc[1][c], 0, 0, 0);
            }
            __syncthreads();   // protect chunk before next overwrite
        }
#pragma unroll
        for (int t2 = 0; t2 < 2; t2++)
#pragma unroll
            for (int c = 0; c < 4; c++)
#pragma unroll
                for (int r = 0; r < 4; r++) {
                    int grow = rbase + t2 * 16 + lk * 4 + r;
                    int col = colbase + c * 16 + lrow;
                    float idv = bf2f(Wtcb[grow * 256 + col]);
                    int rl = grow - et * 64;
                    Mt[rl * 256 + (col ^ ((rl & 7) << 3))] = f2bf(idv - acc[t2][c][r]);
                }
    }
    __syncthreads();
    // ---- phase B: WM rows [et*64..+64) = Mt @ Wl^T (R10 verbatim) ----
    {
        const unsigned short* Wltb = (const unsigned short*)(ws + OFF_WLTB);
        const int rl0 = w_r * 32;
        const int colb = w_c * 32;
        f32x4 acc[2][2];
#pragma unroll
        for (int i = 0; i < 2; i++)
#pragma unroll
            for (int c = 0; c < 2; c++) acc[i][c] = (f32x4){0.f, 0.f, 0.f, 0.f};
        const int arow0 = rl0 + lrow, arow1 = rl0 + 16 + lrow;
        const int asw0 = (arow0 & 7) << 3, asw1 = (arow1 & 7) << 3;
#pragma unroll
        for (int kk = 0; kk < 8; kk++) {
            int ko = kk * 32 + lk * 8;
            bf16x8 a0 = *(const bf16x8*)(Mt + arow0 * 256 + (ko ^ asw0));
            bf16x8 a1 = *(const bf16x8*)(Mt + arow1 * 256 + (ko ^ asw1));
            bf16x8 bfr[2];
#pragma unroll
            for (int c = 0; c < 2; c++)
                bfr[c] = *(const bf16x8*)(Wltb + (colb + c * 16 + lrow) * 256 + ko);
#pragma unroll
            for (int c = 0; c < 2; c++) {
                acc[0][c] = __builtin_amdgcn_mfma_f32_16x16x32_bf16(a0, bfr[c], acc[0][c], 0, 0, 0);
                acc[1][c] = __builtin_amdgcn_mfma_f32_16x16x32_bf16(a1, bfr[c], acc[1][c], 0, 0, 0);
            }
        }
        unsigned short* WMBp = (unsigned short*)(ws + OFF_WMB) + (size_t)b * 32768u;
#pragma unroll
        for (int t2 = 0; t2 < 2; t2++)
#pragma unroll
            for (int c = 0; c < 2; c++)
#pragma unroll
                for (int r = 0; r < 4; r++) {
                    int row = et * 64 + rl0 + t2 * 16 + lk * 4 + r;
                    int col = colb + c * 16 + lrow;
                    WMBp[row * 128 + col] = f2bf(acc[t2][c][r]);
                }
    }
    // ---- tb bias GEMV from LDS Mt ----
    if (t < 64) {
        const int rl = t;
        const int sw = (rl & 7) << 3;
        float s = 0.f;
#pragma unroll 4
        for (int j = 0; j < 32; j++) {
            bf16x8 ch = *(const bf16x8*)(Mt + rl * 256 + ((j * 8) ^ sw));
#pragma unroll
            for (int u = 0; u < 8; u++) s += bl[j * 8 + u] * bf2f((unsigned short)ch[u]);
        }
        ws[OFF_TB + b * DOUT + et * 64 + rl] = s + btc[et * 64 + rl];
    }
}

#define LDP 136

// Fused kS+kF (R9 verbatim, measured 59 us): ONE x staging, ONE tt GEMM, stats
// partials + release arrive, x1 GEMM overlaps wait, t0-only acquire spin.
__global__ __launch_bounds__(256) void kFS(const float* __restrict__ x,
                                           const float* __restrict__ bl,
                                           const float* __restrict__ gamma,
                                           const float* __restrict__ beta,
                                           float* __restrict__ out,
                                           float* __restrict__ ws) {
    const int t = threadIdx.x;
    const int wid = t >> 6, l = t & 63;
    const int b = blockIdx.x;          // fastest dim
    const int nt = blockIdx.y;
    const int n0 = nt * 64;
    const int lrow = l & 15, lk = l >> 4;
    __shared__ unsigned short xs[64 * LDP];
    __shared__ float sp1[4][64], sp2[4][64];
    __shared__ float scs[64], shs[64];

    const float4* xg = (const float4*)(x + (size_t)(b * NN + n0) * DIN);
#pragma unroll
    for (int it = 0; it < 8; it++) {
        int idx = it * 256 + t;
        int row = idx >> 5, kq = idx & 31;
        float4 v = xg[idx];
        ushort4 u;
        u.x = f2bf(v.x); u.y = f2bf(v.y); u.z = f2bf(v.z); u.w = f2bf(v.w);
        *(ushort4*)(xs + row * LDP + kq * 4) = u;
    }
    __syncthreads();

    const int colbase = wid * 64;

    // ---- tt GEMM: acc = x @ WM^T + tb ----
    f32x4 acc[4][4];
#pragma unroll
    for (int rt = 0; rt < 4; rt++)
#pragma unroll
        for (int ct = 0; ct < 4; ct++) acc[rt][ct] = (f32x4){0.f, 0.f, 0.f, 0.f};
    {
        const unsigned short* wbM = (const unsigned short*)(ws + OFF_WMB) + (size_t)b * 32768u;
#pragma unroll
        for (int kk = 0; kk < 4; kk++) {
            int ko = kk * 32 + lk * 8;
            bf16x8 a[4];
#pragma unroll
            for (int rt = 0; rt < 4; rt++)
                a[rt] = *(const bf16x8*)(xs + (rt * 16 + lrow) * LDP + ko);
            bf16x8 bf[4];
#pragma unroll
            for (int ct = 0; ct < 4; ct++)
                bf[ct] = *(const bf16x8*)(wbM + (size_t)(colbase + ct * 16 + lrow) * DIN + ko);
#pragma unroll
            for (int rt = 0; rt < 4; rt++)
#pragma unroll
                for (int ct = 0; ct < 4; ct++)
                    acc[rt][ct] = __builtin_amdgcn_mfma_f32_16x16x32_bf16(a[rt], bf[ct], acc[rt][ct], 0, 0, 0);
        }
#pragma unroll
        for (int ct = 0; ct < 4; ct++) {
            float bv = ws[OFF_TB + b * DOUT + colbase + ct * 16 + lrow];
#pragma unroll
            for (int rt = 0; rt < 4; rt++)
#pragma unroll
                for (int r = 0; r < 4; r++) acc[rt][ct][r] += bv;
        }
    }

    // ---- per-n BN stats partials -> P1/P2, then release arrive ----
    {
        float s1[4][4], s2[4][4];
#pragma unroll
        for (int rt = 0; rt < 4; rt++)
#pragma unroll
            for (int r = 0; r < 4; r++) { s1[rt][r] = 0.f; s2[rt][r] = 0.f; }
#pragma unroll
        for (int rt = 0; rt < 4; rt++)
#pragma unroll
            for (int ct = 0; ct < 4; ct++)
#pragma unroll
                for (int r = 0; r < 4; r++) {
                    float v = acc[rt][ct][r];
                    s1[rt][r] += v; s2[rt][r] += v * v;
                }
#pragma unroll
        for (int off = 1; off < 16; off <<= 1) {
#pragma unroll
            for (int rt = 0; rt < 4; rt++)
#pragma unroll
                for (int r = 0; r < 4; r++) {
                    s1[rt][r] += __shfl_xor(s1[rt][r], off, 64);
                    s2[rt][r] += __shfl_xor(s2[rt][r], off, 64);
                }
        }
        if (lrow == 0) {
#pragma unroll
            for (int rt = 0; rt < 4; rt++)
#pragma unroll
                for (int r = 0; r < 4; r++) {
                    int nidx = rt * 16 + lk * 4 + r;
                    sp1[wid][nidx] = s1[rt][r];
                    sp2[wid][nidx] = s2[rt][r];
                }
        }
    }
    __syncthreads();
    if (t < 64) {
        float S1 = sp1[0][t] + sp1[1][t] + sp1[2][t] + sp1[3][t];
        float S2 = sp2[0][t] + sp2[1][t] + sp2[2][t] + sp2[3][t];
        ws[OFF_P1 + (size_t)b * NN + n0 + t] = S1;
        ws[OFF_P2 + (size_t)b * NN + n0 + t] = S2;
    }
    __syncthreads();   // all partial stores drained (vmcnt(0) at barrier)

    unsigned* cnt = (unsigned*)(ws + OFF_CNT) + (size_t)nt * 32;   // 128B-padded
    if (t == 0)
        __hip_atomic_fetch_add(cnt, 1u, __ATOMIC_RELEASE, __HIP_MEMORY_SCOPE_AGENT);

    // ---- x1 GEMM (overlaps siblings' arrival): acc0 = x @ Wl^T + bl ----
    f32x4 acc0[4][4];
#pragma unroll
    for (int rt = 0; rt < 4; rt++)
#pragma unroll
        for (int ct = 0; ct < 4; ct++) acc0[rt][ct] = (f32x4){0.f, 0.f, 0.f, 0.f};
    {
        const unsigned short* wbL = (const unsigned short*)(ws + OFF_WLB);
#pragma unroll
        for (int kk = 0; kk < 4; kk++) {
            int ko = kk * 32 + lk * 8;
            bf16x8 a[4];
#pragma unroll
            for (int rt = 0; rt < 4; rt++)
                a[rt] = *(const bf16x8*)(xs + (rt * 16 + lrow) * LDP + ko);
            bf16x8 bf[4];
#pragma unroll
            for (int ct = 0; ct < 4; ct++)
                bf[ct] = *(const bf16x8*)(wbL + (size_t)(colbase + ct * 16 + lrow) * DIN + ko);
#pragma unroll
            for (int rt = 0; rt < 4; rt++)
#pragma unroll
                for (int ct = 0; ct < 4; ct++)
                    acc0[rt][ct] = __builtin_amdgcn_mfma_f32_16x16x32_bf16(a[rt], bf[ct], acc0[rt][ct], 0, 0, 0);
        }
#pragma unroll
        for (int ct = 0; ct < 4; ct++) {
            float bv = bl[colbase + ct * 16 + lrow];
#pragma unroll
            for (int rt = 0; rt < 4; rt++)
#pragma unroll
                for (int r = 0; r < 4; r++) acc0[rt][ct][r] += bv;
        }
    }

    // ---- t0-only acquire spin, then fold L2-hot partials ----
    if (t == 0) {
        while (__hip_atomic_load(cnt, __ATOMIC_ACQUIRE, __HIP_MEMORY_SCOPE_AGENT) < (unsigned)BB)
            __builtin_amdgcn_s_sleep(32);
    }
    __syncthreads();

    {
        int n = t & 63, g = t >> 6;          // 4 groups x 8 batches
        float S1 = 0.f, S2 = 0.f;
#pragma unroll
        for (int b2 = g * 8; b2 < g * 8 + 8; b2++) {
            S1 += ws[OFF_P1 + (size_t)b2 * NN + n0 + n];
            S2 += ws[OFF_P2 + (size_t)b2 * NN + n0 + n];
        }
        sp1[g][n] = S1; sp2[g][n] = S2;
    }
    __syncthreads();
    if (t < 64) {
        float S1 = sp1[0][t] + sp1[1][t] + sp1[2][t] + sp1[3][t];
        float S2 = sp2[0][t] + sp2[1][t] + sp2[2][t] + sp2[3][t];
        float mean = S1 * (1.f / 8192.f);
        float var  = S2 * (1.f / 8192.f) - mean * mean;
        float sc = gamma[n0 + t] * rsqrtf(fmaxf(var, 0.f) + 1e-5f);
        scs[t] = sc;
        shs[t] = beta[n0 + t] - mean * sc;
    }
    __syncthreads();

    // ---- epilogue straight from registers: out = (x1 + relu(bn(tt)))*g + hb ----
    float gv[4], hbv[4];
#pragma unroll
    for (int ct = 0; ct < 4; ct++) {
        int o = colbase + ct * 16 + lrow;
        gv[ct]  = ws[OFF_G  + b * DOUT + o];
        hbv[ct] = ws[OFF_HB + b * DOUT + o];
    }
#pragma unroll
    for (int rt = 0; rt < 4; rt++)
#pragma unroll
        for (int r = 0; r < 4; r++) {
            int nidx = rt * 16 + lk * 4 + r;
            float sc = scs[nidx], sh = shs[nidx];
            int n = n0 + nidx;
#pragma unroll
            for (int ct = 0; ct < 4; ct++) {
                int o = colbase + ct * 16 + lrow;
                float rv = fmaxf(acc[rt][ct][r] * sc + sh, 0.f);
                out[(size_t)((b * NN + n) * DOUT) + o] = (acc0[rt][ct][r] + rv) * gv[ct] + hbv[ct];
            }
        }
}

extern "C" void kernel_launch(void* const* d_in, const int* in_sizes, int n_in,
                              void* d_out, int out_size, void* d_ws, size_t ws_size,
                              hipStream_t stream) {
    const float* ctx   = (const float*)d_in[0];
    const float* x     = (const float*)d_in[1];
    const float* Wl    = (const float*)d_in[2];
    const float* bl    = (const float*)d_in[3];
    const float* Whb   = (const float*)d_in[4];
    const float* Wg    = (const float*)d_in[5];
    const float* bg    = (const float*)d_in[6];
    const float* Wk    = (const float*)d_in[7];
    const float* Wv    = (const float*)d_in[8];
    const float* Wtc   = (const float*)d_in[9];
    const float* btc   = (const float*)d_in[10];
    const float* gamma = (const float*)d_in[11];
    const float* beta  = (const float*)d_in[12];
    float* out = (float*)d_out;
    float* ws  = (float*)d_ws;

    kW  <<<75, 256, 0, stream>>>(Wl, Wtc, Wk, Wv, Wg, Whb, ctx, bg, ws);
    kQ  <<<dim3(4, BB), 512, 0, stream>>>(bl, btc, ws);
    kFS <<<dim3(BB, 32), 256, 0, stream>>>(x, bl, gamma, beta, out, ws);
}